// Round 3
// baseline (1712.187 us; speedup 1.0000x reference)
//
#include <hip/hip_runtime.h>
#include <math.h>

// Problem dims (fixed by reference)
#define S_DIM 512
#define B_DIM 64
#define IN_DIM 512
#define H_DIM 1024
#define OUT_DIM 512
#define BH (B_DIM * H_DIM)      // 65536

typedef unsigned short ushort_t;
typedef unsigned int uint_t;
using f32x4 = __attribute__((ext_vector_type(4))) float;
using f16x8 = __attribute__((ext_vector_type(8))) _Float16;  // 8 f16 (4 VGPRs)

#define LO_SCALE 2048.0f          // 2^11
#define LO_INV   (1.0f / 2048.0f)

// ---- fp32 -> f16 hi/lo split: x ~= hi + lo/2048 (lo holds residual * 2^11) ----
__device__ __forceinline__ void split_f16(float v, ushort_t& hi, ushort_t& lo) {
    _Float16 h = (_Float16)v;
    float r = (v - (float)h) * LO_SCALE;
    _Float16 l = (_Float16)r;
    hi = __builtin_bit_cast(ushort_t, h);
    lo = __builtin_bit_cast(ushort_t, l);
}

// ---- fast transcendentals (v_exp_f32 / v_rcp_f32 based) ----
__device__ __forceinline__ float frcp(float x) { return __builtin_amdgcn_rcpf(x); }
__device__ __forceinline__ float fsig(float z) { return frcp(1.f + __expf(-z)); }
__device__ __forceinline__ float ftanh(float z) { return 1.f - 2.f * frcp(1.f + __expf(2.f * z)); }

__device__ __forceinline__ void gload_lds16(const ushort_t* g, ushort_t* l) {
    __builtin_amdgcn_global_load_lds(
        (const __attribute__((address_space(1))) void*)g,
        (__attribute__((address_space(3))) void*)l, 16, 0, 0);
}

// ---------------- weight transpose + split: W[K,N] f32 -> Whi/Wlo [N,K] f16 ----------------
__global__ __launch_bounds__(256) void transpose_split_f16(
    const float* __restrict__ W, ushort_t* __restrict__ Whi, ushort_t* __restrict__ Wlo,
    int K, int N)
{
    __shared__ float tile[32][33];
    const int k0 = blockIdx.y * 32, n0 = blockIdx.x * 32;
    const int tx = threadIdx.x & 31, ty = threadIdx.x >> 5;   // ty 0..7
#pragma unroll
    for (int r = 0; r < 32; r += 8)
        tile[ty + r][tx] = W[(size_t)(k0 + ty + r) * N + n0 + tx];
    __syncthreads();
#pragma unroll
    for (int r = 0; r < 32; r += 8) {
        ushort_t hi, lo;
        split_f16(tile[tx][ty + r], hi, lo);
        const size_t o = (size_t)(n0 + ty + r) * K + k0 + tx;
        Whi[o] = hi;
        Wlo[o] = lo;
    }
}

// ---------------- f32 -> f16 hi/lo split (activations, contiguous) ----------------
__global__ __launch_bounds__(256) void convert_split_f16(
    const float* __restrict__ src, ushort_t* __restrict__ dhi, ushort_t* __restrict__ dlo,
    int n)  // n % 4 == 0
{
    const int i = (blockIdx.x * 256 + threadIdx.x) * 4;
    if (i < n) {
        float4 v = *(const float4*)(src + i);
        ushort4 h, l;
        split_f16(v.x, h.x, l.x); split_f16(v.y, h.y, l.y);
        split_f16(v.z, h.z, l.z); split_f16(v.w, h.w, l.w);
        *(ushort4*)(dhi + i) = h;
        *(ushort4*)(dlo + i) = l;
    }
}

// ---------------- split-precision f16 MFMA GEMM: C = A @ W + bias (fp32 out) ----------------
// A = Ahi + Alo/2048 [M,K]; W transposed: Whi/Wlo [N,K]. bias fp32 [N]. C fp32 [M,N].
//
// v3 (counter-driven): v2's swizzle killed bank conflicts (1.26e7 -> 0) but wall
// unchanged -> 2-phase drain is the critical path (regime-gate, m252-analog).
// This version adds real pipeline depth (T3+T4+T5):
//  - 512-thread block, tile 128(M)x256(N), 8 waves 2Mx4N, per-wave 64x64 (same
//    per-wave frag/MFMA counts as v2 -> same regs), 1 block/CU, 8 waves/CU.
//  - TRIPLE-buffered LDS (144 KB static; gfx950 allows up to 160 KB/workgroup),
//    prefetch depth 2.
//  - counted vmcnt: steady-state s_waitcnt vmcnt(6) (wait only oldest tile's 6
//    loads; next tile's 6 stay in flight across the raw s_barrier). Never
//    drains to 0 in the main loop; tail peels to vmcnt(0).
//  - s_setprio(1) around the MFMA cluster (wave role-split now exists).
// Hazards: buffer (t+2)%3 last read at iter t-1; those ds_reads retire before
// that wave's MFMAs issue, and the top-of-t barrier orders all waves past them
// before the overwrite. vmcnt is per-wave FIFO; vmcnt(6)+barrier => tile t
// globally complete before ds_read.
__global__ __launch_bounds__(512, 1) void mfma_gemm3_split(
    const ushort_t* __restrict__ Ahi, const ushort_t* __restrict__ Alo,
    const ushort_t* __restrict__ Wh0, const ushort_t* __restrict__ Wl0,
    const ushort_t* __restrict__ Wh1, const ushort_t* __restrict__ Wl1,
    const ushort_t* __restrict__ Wh2, const ushort_t* __restrict__ Wl2,
    const float* __restrict__ b0, const float* __restrict__ b1, const float* __restrict__ b2,
    float* __restrict__ C0, float* __restrict__ C1, float* __restrict__ C2,
    int M, int N, int K)
{
    const int NB = N >> 8;                 // 256-wide N blocks
    const int inner = blockIdx.x % (3 * NB);
    const int mb = blockIdx.x / (3 * NB);
    const int nb = inner % NB;
    const int z  = inner / NB;

    const ushort_t* __restrict__ Wh = (z == 0) ? Wh0 : (z == 1) ? Wh1 : Wh2;
    const ushort_t* __restrict__ Wl = (z == 0) ? Wl0 : (z == 1) ? Wl1 : Wl2;
    const float* __restrict__ bias  = (z == 0) ? b0  : (z == 1) ? b1  : b2;
    float* __restrict__ C           = (z == 0) ? C0  : (z == 1) ? C1  : C2;

    // triple-buffered: A 2x(3x8KB) + B 2x(3x16KB) = 144KB
    __shared__ __align__(16) ushort_t AsH[3][128 * 32];
    __shared__ __align__(16) ushort_t AsL[3][128 * 32];
    __shared__ __align__(16) ushort_t BsH[3][256 * 32];
    __shared__ __align__(16) ushort_t BsL[3][256 * 32];

    const int tid  = threadIdx.x;
    const int lane = tid & 63;
    const int wave = tid >> 6;           // 0..7
    const int quad = lane >> 4;
    const int l16  = lane & 15;
    const int wm   = wave >> 2;          // 0..1  (M: 2 x 64)
    const int wn   = wave & 3;           // 0..3  (N: 4 x 64)

    const int row0 = mb * 128;
    const int col0 = nb * 256;

    f32x4 accP[4][4] = {};
    f32x4 accQ[4][4] = {};

    // Stage addressing (per thread, per tile): A-tile 128x32 = 512 chunks (1/thr),
    // B-tile 256x32 = 1024 chunks (2/thr). 6 gload_lds per thread per stage.
    // Global source chunk pre-swizzled (kc ^ (r>>1)&3) so the linear LDS dest
    // lands bank-swizzled (rule-21 both-sides).
    const int ca  = tid;
    const int ra  = ca >> 2;
    const int ka  = (ca & 3) ^ ((ra >> 1) & 3);
    const size_t gaoff = (size_t)(row0 + ra) * K + ka * 8;

    const int cb0 = tid,        rb0 = cb0 >> 2, kb0 = (cb0 & 3) ^ ((rb0 >> 1) & 3);
    const int cb1 = tid + 512,  rb1 = cb1 >> 2, kb1 = (cb1 & 3) ^ ((rb1 >> 1) & 3);
    const size_t gboff0 = (size_t)(col0 + rb0) * K + kb0 * 8;
    const size_t gboff1 = (size_t)(col0 + rb1) * K + kb1 * 8;

    auto STAGE = [&](int buf, int t) {
        const int k0 = t << 5;
        gload_lds16(Ahi + gaoff + k0, &AsH[buf][ca * 8]);
        gload_lds16(Alo + gaoff + k0, &AsL[buf][ca * 8]);
        gload_lds16(Wh + gboff0 + k0, &BsH[buf][cb0 * 8]);
        gload_lds16(Wl + gboff0 + k0, &BsL[buf][cb0 * 8]);
        gload_lds16(Wh + gboff1 + k0, &BsH[buf][cb1 * 8]);
        gload_lds16(Wl + gboff1 + k0, &BsL[buf][cb1 * 8]);
    };

    const int nt = K >> 5;               // >= 16 always
    STAGE(0, 0);
    STAGE(1, 1);

    // read-side swizzle: row bits 0..3 == l16 -> (row>>1)&3 == (l16>>1)&3
    const int gq  = (quad ^ ((l16 >> 1) & 3)) * 8;
    const int aro = (wm * 64 + l16) * 32 + gq;
    const int bro = (wn * 64 + l16) * 32 + gq;

    int cur = 0;
    for (int t = 0; t < nt; ++t) {
        if (t + 2 < nt) {
            asm volatile("s_waitcnt vmcnt(6)" ::: "memory");   // oldest tile landed
        } else {
            asm volatile("s_waitcnt vmcnt(0)" ::: "memory");   // tail drain
        }
        __builtin_amdgcn_sched_barrier(0);
        __builtin_amdgcn_s_barrier();

        if (t + 2 < nt) {
            int nx = cur + 2; if (nx >= 3) nx -= 3;
            STAGE(nx, t + 2);
        }

        f16x8 ah[4], al[4], bh[4], bl[4];
#pragma unroll
        for (int i = 0; i < 4; ++i) {
            const int ro = aro + i * 512;     // +16 rows * 32
            ah[i] = *(const f16x8*)&AsH[cur][ro];
            al[i] = *(const f16x8*)&AsL[cur][ro];
        }
#pragma unroll
        for (int j = 0; j < 4; ++j) {
            const int ro = bro + j * 512;
            bh[j] = *(const f16x8*)&BsH[cur][ro];
            bl[j] = *(const f16x8*)&BsL[cur][ro];
        }

        __builtin_amdgcn_s_setprio(1);
#pragma unroll
        for (int i = 0; i < 4; ++i)
#pragma unroll
            for (int j = 0; j < 4; ++j) {
                accP[i][j] = __builtin_amdgcn_mfma_f32_16x16x32_f16(ah[i], bh[j], accP[i][j], 0, 0, 0);
                accQ[i][j] = __builtin_amdgcn_mfma_f32_16x16x32_f16(ah[i], bl[j], accQ[i][j], 0, 0, 0);
                accQ[i][j] = __builtin_amdgcn_mfma_f32_16x16x32_f16(al[i], bh[j], accQ[i][j], 0, 0, 0);
            }
        __builtin_amdgcn_s_setprio(0);

        cur = (cur + 1 == 3) ? 0 : cur + 1;
    }

    // epilogue: C/D layout col = lane&15, row = quad*4 + reg
#pragma unroll
    for (int i = 0; i < 4; ++i) {
        const int row = row0 + wm * 64 + i * 16 + quad * 4;
#pragma unroll
        for (int j = 0; j < 4; ++j) {
            const int col = col0 + wn * 64 + j * 16 + l16;
            const float bv = bias[col];
#pragma unroll
            for (int r = 0; r < 4; ++r)
                C[(size_t)(row + r) * N + col] = accP[i][j][r] + accQ[i][j][r] * LO_INV + bv;
        }
    }
}

// ---------------- single-precision f16 MFMA GEMM (decoder): C = A @ W + bias ----------------
// Small (~20us/dispatch) -> kept at the v2 swizzled 2-buffer structure.
__global__ __launch_bounds__(256, 2) void mfma_gemm_dec(
    const ushort_t* __restrict__ A, const ushort_t* __restrict__ Wt,
    const float* __restrict__ bias, float* __restrict__ C,
    int M, int N, int K)
{
    const int NB = N >> 7;
    const int mb = blockIdx.x / NB;
    const int nb = blockIdx.x % NB;

    __shared__ __align__(16) ushort_t As[2][128 * 32];
    __shared__ __align__(16) ushort_t Bs[2][128 * 32];

    const int tid  = threadIdx.x;
    const int lane = tid & 63;
    const int wave = tid >> 6;
    const int quad = lane >> 4;
    const int l16  = lane & 15;
    const int wm   = wave >> 1;
    const int wn   = wave & 1;

    const int row0 = mb * 128;
    const int col0 = nb * 128;

    f32x4 acc[4][4] = {};

    auto STAGE = [&](int buf, int k0) {
#pragma unroll
        for (int i = 0; i < 2; ++i) {
            const int c  = tid + i * 256;
            const int r  = c >> 2;
            const int kc = (c & 3) ^ ((r >> 1) & 3);
            gload_lds16(A  + (size_t)(row0 + r) * K + k0 + kc * 8, &As[buf][c * 8]);
            gload_lds16(Wt + (size_t)(col0 + r) * K + k0 + kc * 8, &Bs[buf][c * 8]);
        }
    };

    const int nt = K >> 5;
    STAGE(0, 0);
    int cur = 0;
    const int gq = (quad ^ ((l16 >> 1) & 3)) * 8;

    for (int t = 0; t < nt; ++t) {
        __syncthreads();
        if (t + 1 < nt) STAGE(cur ^ 1, (t + 1) << 5);

        f16x8 af[4], bf[4];
#pragma unroll
        for (int i = 0; i < 4; ++i)
            af[i] = *(const f16x8*)&As[cur][(wm * 64 + i * 16 + l16) * 32 + gq];
#pragma unroll
        for (int j = 0; j < 4; ++j)
            bf[j] = *(const f16x8*)&Bs[cur][(wn * 64 + j * 16 + l16) * 32 + gq];

#pragma unroll
        for (int i = 0; i < 4; ++i)
#pragma unroll
            for (int j = 0; j < 4; ++j)
                acc[i][j] = __builtin_amdgcn_mfma_f32_16x16x32_f16(af[i], bf[j], acc[i][j], 0, 0, 0);
        cur ^= 1;
    }

#pragma unroll
    for (int i = 0; i < 4; ++i) {
        const int row = row0 + wm * 64 + i * 16 + quad * 4;
#pragma unroll
        for (int j = 0; j < 4; ++j) {
            const int col = col0 + wn * 64 + j * 16 + l16;
            const float bv = bias[col];
#pragma unroll
            for (int r = 0; r < 4; ++r)
                C[(size_t)(row + r) * N + col] = acc[i][j][r] + bv;
        }
    }
}

// ---------------- BRC scan: 1 elem/thread, 8-deep prefetch, fast transcendentals ----------------
// fp32 gates in, y out as f16 hi (+ optional lo plane), fp32 recurrence.
template <bool WRITE_LO>
__global__ __launch_bounds__(256) void brc_scan_v3(
    const float* __restrict__ xa, const float* __restrict__ xc,
    const float* __restrict__ xh, const float* __restrict__ wa,
    const float* __restrict__ wc, const float* __restrict__ h_in,
    ushort_t* __restrict__ yhi, ushort_t* __restrict__ ylo,
    float* __restrict__ h_out, int T_c)
{
    const int idx = blockIdx.x * 256 + threadIdx.x;   // 0..BH-1
    const int j = idx & (H_DIM - 1);
    float h = h_in[idx];
    const float waj = wa[j], wcj = wc[j];

    float pa[8], pc[8], ph[8];
#pragma unroll
    for (int d = 0; d < 8; ++d) {
        const int dd = (d < T_c) ? d : 0;
        const size_t b = (size_t)dd * BH + idx;
        pa[d] = xa[b]; pc[d] = xc[b]; ph[d] = xh[b];
    }

#pragma unroll 8
    for (int t = 0; t < T_c; ++t) {
        const int s = t & 7;
        const float ca = pa[s], cc = pc[s], ch = ph[s];
        const int tn = t + 8;
        if (tn < T_c) {
            const size_t b = (size_t)tn * BH + idx;
            pa[s] = xa[b]; pc[s] = xc[b]; ph[s] = xh[b];
        }
        const float a = 1.f + ftanh(ca + waj * h);
        const float c = fsig(cc + wcj * h);
        h = c * h + (1.f - c) * ftanh(ch + a * h);

        ushort_t hh, hl;
        split_f16(h, hh, hl);
        const size_t ob = (size_t)t * BH + idx;
        yhi[ob] = hh;
        if (WRITE_LO) ylo[ob] = hl;
    }
    h_out[idx] = h;
}

extern "C" void kernel_launch(void* const* d_in, const int* in_sizes, int n_in,
                              void* d_out, int out_size, void* d_ws, size_t ws_size,
                              hipStream_t stream) {
    const float* x    = (const float*)d_in[0];   // [S,B,IN]
    const float* h0   = (const float*)d_in[1];   // [L,B,H]
    const float* Ua0  = (const float*)d_in[2];
    const float* Uc0  = (const float*)d_in[3];
    const float* Uh0  = (const float*)d_in[4];
    const float* wa0  = (const float*)d_in[5];
    const float* wc0  = (const float*)d_in[6];
    const float* ba0  = (const float*)d_in[7];
    const float* bc0  = (const float*)d_in[8];
    const float* bh0  = (const float*)d_in[9];
    const float* Ua1  = (const float*)d_in[10];
    const float* Uc1  = (const float*)d_in[11];
    const float* Uh1  = (const float*)d_in[12];
    const float* wa1  = (const float*)d_in[13];
    const float* wc1  = (const float*)d_in[14];
    const float* ba1  = (const float*)d_in[15];
    const float* bc1  = (const float*)d_in[16];
    const float* bh1  = (const float*)d_in[17];
    const float* Wdec = (const float*)d_in[18];
    const float* bdec = (const float*)d_in[19];

    float* outF = (float*)d_out;
    float* out_seq  = outF;                                   // [S,B,OUT]
    float* h_last0  = outF + (size_t)S_DIM * B_DIM * OUT_DIM; // [B,H]
    float* h_last1  = h_last0 + BH;                           // [B,H]

    // ---- workspace carve-up ----
    char* wsb = (char*)d_ws;
    size_t off = 0;
    auto alloc = [&](size_t bytes) -> void* {
        void* p = wsb + off;
        off += (bytes + 255) & ~(size_t)255;
        return p;
    };
    const size_t szL0 = (size_t)IN_DIM * H_DIM;
    const size_t szL1 = (size_t)H_DIM * H_DIM;
    const size_t szD  = (size_t)H_DIM * OUT_DIM;
    ushort_t *Wa0h = (ushort_t*)alloc(szL0 * 2), *Wa0l = (ushort_t*)alloc(szL0 * 2);
    ushort_t *Wc0h = (ushort_t*)alloc(szL0 * 2), *Wc0l = (ushort_t*)alloc(szL0 * 2);
    ushort_t *Wh0h = (ushort_t*)alloc(szL0 * 2), *Wh0l = (ushort_t*)alloc(szL0 * 2);
    ushort_t *Wa1h = (ushort_t*)alloc(szL1 * 2), *Wa1l = (ushort_t*)alloc(szL1 * 2);
    ushort_t *Wc1h = (ushort_t*)alloc(szL1 * 2), *Wc1l = (ushort_t*)alloc(szL1 * 2);
    ushort_t *Wh1h = (ushort_t*)alloc(szL1 * 2), *Wh1l = (ushort_t*)alloc(szL1 * 2);
    ushort_t *Wdh  = (ushort_t*)alloc(szD * 2),  *Wdl  = (ushort_t*)alloc(szD * 2);

    // Per-chunk bytes: x hi/lo + 3 fp32 gate planes + y0 hi/lo + y1 hi (no y1 lo)
    const size_t perT = (size_t)2 * B_DIM * IN_DIM * 2 + (size_t)3 * BH * 4 + (size_t)3 * BH * 2;
    int T_c = 512;
    while (T_c > 1 && off + (size_t)T_c * perT + 4096 > ws_size) T_c >>= 1;
    const size_t chunk_elems = (size_t)T_c * BH;
    const size_t xchunk_elems = (size_t)T_c * B_DIM * IN_DIM;

    ushort_t* xhib = (ushort_t*)alloc(xchunk_elems * 2);
    ushort_t* xlob = (ushort_t*)alloc(xchunk_elems * 2);
    float* g_a = (float*)alloc(chunk_elems * 4);
    float* g_c = (float*)alloc(chunk_elems * 4);
    float* g_h = (float*)alloc(chunk_elems * 4);
    ushort_t* y0h = (ushort_t*)alloc(chunk_elems * 2);
    ushort_t* y0l = (ushort_t*)alloc(chunk_elems * 2);
    ushort_t* y1h = (ushort_t*)alloc(chunk_elems * 2);

    const int n_chunks = S_DIM / T_c;
    const int Mc = T_c * B_DIM;

    // ---- one-time per call: weight transpose+split ----
    transpose_split_f16<<<dim3(H_DIM / 32, IN_DIM / 32), 256, 0, stream>>>(Ua0, Wa0h, Wa0l, IN_DIM, H_DIM);
    transpose_split_f16<<<dim3(H_DIM / 32, IN_DIM / 32), 256, 0, stream>>>(Uc0, Wc0h, Wc0l, IN_DIM, H_DIM);
    transpose_split_f16<<<dim3(H_DIM / 32, IN_DIM / 32), 256, 0, stream>>>(Uh0, Wh0h, Wh0l, IN_DIM, H_DIM);
    transpose_split_f16<<<dim3(H_DIM / 32, H_DIM / 32), 256, 0, stream>>>(Ua1, Wa1h, Wa1l, H_DIM, H_DIM);
    transpose_split_f16<<<dim3(H_DIM / 32, H_DIM / 32), 256, 0, stream>>>(Uc1, Wc1h, Wc1l, H_DIM, H_DIM);
    transpose_split_f16<<<dim3(H_DIM / 32, H_DIM / 32), 256, 0, stream>>>(Uh1, Wh1h, Wh1l, H_DIM, H_DIM);
    transpose_split_f16<<<dim3(OUT_DIM / 32, H_DIM / 32), 256, 0, stream>>>(Wdec, Wdh, Wdl, H_DIM, OUT_DIM);

    dim3 blk512(512), blk(256);
    const int grid_g = (Mc / 128) * (H_DIM / 256) * 3;   // 1D swizzled, 256-wide N blocks
    const int grid_d = (OUT_DIM / 128) * (Mc / 128);
    dim3 grid_scan(BH / 256);

    for (int ci = 0; ci < n_chunks; ++ci) {
        const float* x_chunk = x + (size_t)ci * Mc * IN_DIM;
        float* out_chunk = out_seq + (size_t)ci * Mc * OUT_DIM;

        // split x chunk -> hi/lo f16 planes
        convert_split_f16<<<dim3((int)(xchunk_elems / 4 / 256)), blk, 0, stream>>>(
            x_chunk, xhib, xlob, (int)xchunk_elems);

        // layer 0 gates: x @ U{a,c,h}0 + b -> fp32 gate buffers
        mfma_gemm3_split<<<dim3(grid_g), blk512, 0, stream>>>(
            xhib, xlob, Wa0h, Wa0l, Wc0h, Wc0l, Wh0h, Wh0l,
            ba0, bc0, bh0, g_a, g_c, g_h, Mc, H_DIM, IN_DIM);
        brc_scan_v3<true><<<grid_scan, blk, 0, stream>>>(
            g_a, g_c, g_h, wa0, wc0, (ci == 0) ? h0 : h_last0, y0h, y0l, h_last0, T_c);

        // layer 1 gates: y0 @ U{a,c,h}1 + b
        mfma_gemm3_split<<<dim3(grid_g), blk512, 0, stream>>>(
            y0h, y0l, Wa1h, Wa1l, Wc1h, Wc1l, Wh1h, Wh1l,
            ba1, bc1, bh1, g_a, g_c, g_h, Mc, H_DIM, H_DIM);
        brc_scan_v3<false><<<grid_scan, blk, 0, stream>>>(
            g_a, g_c, g_h, wa1, wc1, (ci == 0) ? (h0 + BH) : h_last1, y1h, nullptr, h_last1, T_c);

        // decoder: y1(hi) @ Wdec + bdec -> fp32 out
        mfma_gemm_dec<<<dim3(grid_d), blk, 0, stream>>>(
            y1h, Wdh, bdec, out_chunk, Mc, OUT_DIM, H_DIM);
    }
}

// Round 4
// 1573.158 us; speedup vs baseline: 1.0884x; 1.0884x over previous
//
#include <hip/hip_runtime.h>
#include <math.h>

// Problem dims (fixed by reference)
#define S_DIM 512
#define B_DIM 64
#define IN_DIM 512
#define H_DIM 1024
#define OUT_DIM 512
#define BH (B_DIM * H_DIM)      // 65536

typedef unsigned short ushort_t;
typedef unsigned int uint_t;
using f32x4 = __attribute__((ext_vector_type(4))) float;
using f16x8 = __attribute__((ext_vector_type(8))) _Float16;  // 8 f16 (4 VGPRs)

#define LO_SCALE 2048.0f          // 2^11
#define LO_INV   (1.0f / 2048.0f)

// ---- fp32 -> f16 hi/lo split: x ~= hi + lo/2048 (lo holds residual * 2^11) ----
__device__ __forceinline__ void split_f16(float v, ushort_t& hi, ushort_t& lo) {
    _Float16 h = (_Float16)v;
    float r = (v - (float)h) * LO_SCALE;
    _Float16 l = (_Float16)r;
    hi = __builtin_bit_cast(ushort_t, h);
    lo = __builtin_bit_cast(ushort_t, l);
}

// ---- fast transcendentals (v_exp_f32 / v_rcp_f32 based) ----
__device__ __forceinline__ float frcp(float x) { return __builtin_amdgcn_rcpf(x); }
__device__ __forceinline__ float fsig(float z) { return frcp(1.f + __expf(-z)); }
__device__ __forceinline__ float ftanh(float z) { return 1.f - 2.f * frcp(1.f + __expf(2.f * z)); }

__device__ __forceinline__ void gload_lds16(const ushort_t* g, ushort_t* l) {
    __builtin_amdgcn_global_load_lds(
        (const __attribute__((address_space(1))) void*)g,
        (__attribute__((address_space(3))) void*)l, 16, 0, 0);
}

// Bijective XCD-chunked swizzle (T1): dispatch round-robins blockIdx across the
// 8 XCDs; remap so each XCD gets a CONTIGUOUS chunk of logical work ids. All
// consumers of an A-strip (adjacent logical ids) then share one XCD's L2.
__device__ __forceinline__ int xcd_swizzle(int bid, int nwg) {
    if (nwg & 7) return bid;             // guard (not hit for our grids)
    const int per = nwg >> 3;
    return (bid & 7) * per + (bid >> 3);
}

// ---------------- weight transpose + split: W[K,N] f32 -> Whi/Wlo [N,K] f16 ----------------
__global__ __launch_bounds__(256) void transpose_split_f16(
    const float* __restrict__ W, ushort_t* __restrict__ Whi, ushort_t* __restrict__ Wlo,
    int K, int N)
{
    __shared__ float tile[32][33];
    const int k0 = blockIdx.y * 32, n0 = blockIdx.x * 32;
    const int tx = threadIdx.x & 31, ty = threadIdx.x >> 5;   // ty 0..7
#pragma unroll
    for (int r = 0; r < 32; r += 8)
        tile[ty + r][tx] = W[(size_t)(k0 + ty + r) * N + n0 + tx];
    __syncthreads();
#pragma unroll
    for (int r = 0; r < 32; r += 8) {
        ushort_t hi, lo;
        split_f16(tile[tx][ty + r], hi, lo);
        const size_t o = (size_t)(n0 + ty + r) * K + k0 + tx;
        Whi[o] = hi;
        Wlo[o] = lo;
    }
}

// ---------------- f32 -> f16 hi/lo split (activations, contiguous) ----------------
__global__ __launch_bounds__(256) void convert_split_f16(
    const float* __restrict__ src, ushort_t* __restrict__ dhi, ushort_t* __restrict__ dlo,
    int n)  // n % 4 == 0
{
    const int i = (blockIdx.x * 256 + threadIdx.x) * 4;
    if (i < n) {
        float4 v = *(const float4*)(src + i);
        ushort4 h, l;
        split_f16(v.x, h.x, l.x); split_f16(v.y, h.y, l.y);
        split_f16(v.z, h.z, l.z); split_f16(v.w, h.w, l.w);
        *(ushort4*)(dhi + i) = h;
        *(ushort4*)(dlo + i) = l;
    }
}

// ---------------- split-precision f16 MFMA GEMM: C = A @ W + bias (fp32 out) ----------------
// A = Ahi + Alo/2048 [M,K]; W transposed: Whi/Wlo [N,K]. bias fp32 [N]. C fp32 [M,N].
// 1D swizzled grid: M-strip OUTER, (gate, N-block) INNER.
//
// v4 (counter-driven; v3 post-mortem): v3's 512-thr/1-block-per-CU counted-vmcnt
// pipeline REGRESSED (165->183us, MfmaUtil 37%) - lockstep waves lost v2's
// 2-block-per-CU stagger, and FETCH rose. Root remaining stall: A-strips are
// re-fetched from HBM 3-4x (FETCH 154MB vs ~46MB ideal) because the 24 consumer
// blocks of each strip round-robin across XCDs. v4 = proven v2 structure +:
//  - T1 XCD-chunked swizzle: consumers of an A-strip share one XCD's L2
//    (strip working set ~1.5MB << 4MB L2) -> staging becomes L2-hit.
//  - ds_reads issued BEFORE the prefetch stage; stage split in two halves
//    interleaved between the two MFMA quadrant clusters (fine interleave,
//    no sync-structure change; compiler owns all waitcnts).
//  - XOR bank swizzle kept (conflicts measured 0).
__global__ __launch_bounds__(256, 2) void mfma_gemm3_split(
    const ushort_t* __restrict__ Ahi, const ushort_t* __restrict__ Alo,
    const ushort_t* __restrict__ Wh0, const ushort_t* __restrict__ Wl0,
    const ushort_t* __restrict__ Wh1, const ushort_t* __restrict__ Wl1,
    const ushort_t* __restrict__ Wh2, const ushort_t* __restrict__ Wl2,
    const float* __restrict__ b0, const float* __restrict__ b1, const float* __restrict__ b2,
    float* __restrict__ C0, float* __restrict__ C1, float* __restrict__ C2,
    int M, int N, int K)
{
    const int NB = N >> 7;                 // N-blocks (128 wide)
    const int lb = xcd_swizzle(blockIdx.x, gridDim.x);
    const int inner = lb % (3 * NB);
    const int mb = lb / (3 * NB);
    const int nb = inner % NB;
    const int z  = inner / NB;

    const ushort_t* __restrict__ Wh = (z == 0) ? Wh0 : (z == 1) ? Wh1 : Wh2;
    const ushort_t* __restrict__ Wl = (z == 0) ? Wl0 : (z == 1) ? Wl1 : Wl2;
    const float* __restrict__ bias  = (z == 0) ? b0  : (z == 1) ? b1  : b2;
    float* __restrict__ C           = (z == 0) ? C0  : (z == 1) ? C1  : C2;

    // double-buffered: 4 planes x 8KB x 2 = 64KB
    __shared__ __align__(16) ushort_t AsH[2][128 * 32];
    __shared__ __align__(16) ushort_t AsL[2][128 * 32];
    __shared__ __align__(16) ushort_t BsH[2][128 * 32];
    __shared__ __align__(16) ushort_t BsL[2][128 * 32];

    const int tid  = threadIdx.x;
    const int lane = tid & 63;
    const int wave = tid >> 6;
    const int quad = lane >> 4;
    const int l16  = lane & 15;
    const int wm   = wave >> 1;          // 0..1
    const int wn   = wave & 1;           // 0..1

    const int row0 = mb * 128;
    const int col0 = nb * 128;

    f32x4 accP[4][4] = {};
    f32x4 accQ[4][4] = {};

    // stage half h (h=0,1) of one BK=32 K-tile into buffer `buf`; LDS dest linear
    // (global_load_lds requirement), global source k-chunk pre-swizzled.
    auto STAGE_HALF = [&](int buf, int k0, int h) {
        const int c  = tid + h * 256;       // 0..511
        const int r  = c >> 2;              // 0..127
        const int kc = (c & 3) ^ ((r >> 1) & 3);   // swizzled source chunk
        const size_t ga = (size_t)(row0 + r) * K + k0 + kc * 8;
        const size_t gb = (size_t)(col0 + r) * K + k0 + kc * 8;
        gload_lds16(Ahi + ga, &AsH[buf][c * 8]);
        gload_lds16(Alo + ga, &AsL[buf][c * 8]);
        gload_lds16(Wh  + gb, &BsH[buf][c * 8]);
        gload_lds16(Wl  + gb, &BsL[buf][c * 8]);
    };

    const int nt = K >> 5;
    STAGE_HALF(0, 0, 0);
    STAGE_HALF(0, 0, 1);
    int cur = 0;
    // read-side swizzle: for row = wm*64 + i*16 + l16, ((row>>1)&3) == ((l16>>1)&3)
    const int gq = (quad ^ ((l16 >> 1) & 3)) * 8;   // granule offset in ushorts

    for (int t = 0; t < nt; ++t) {
        __syncthreads();                 // buf[cur] staged, all prior reads done

        // ds_reads FIRST so MFMAs can start as soon as lgkmcnt clears
        f16x8 ah[4], al[4], bh[4], bl[4];
#pragma unroll
        for (int i = 0; i < 4; ++i) {
            const int ro = (wm * 64 + i * 16 + l16) * 32 + gq;
            ah[i] = *(const f16x8*)&AsH[cur][ro];
            al[i] = *(const f16x8*)&AsL[cur][ro];
        }
#pragma unroll
        for (int j = 0; j < 4; ++j) {
            const int ro = (wn * 64 + j * 16 + l16) * 32 + gq;
            bh[j] = *(const f16x8*)&BsH[cur][ro];
            bl[j] = *(const f16x8*)&BsL[cur][ro];
        }

        // prefetch half 1, then first MFMA quadrant-pair, then half 2, then rest
        if (t + 1 < nt) STAGE_HALF(cur ^ 1, (t + 1) << 5, 0);

#pragma unroll
        for (int i = 0; i < 2; ++i)
#pragma unroll
            for (int j = 0; j < 4; ++j) {
                accP[i][j] = __builtin_amdgcn_mfma_f32_16x16x32_f16(ah[i], bh[j], accP[i][j], 0, 0, 0);
                accQ[i][j] = __builtin_amdgcn_mfma_f32_16x16x32_f16(ah[i], bl[j], accQ[i][j], 0, 0, 0);
                accQ[i][j] = __builtin_amdgcn_mfma_f32_16x16x32_f16(al[i], bh[j], accQ[i][j], 0, 0, 0);
            }

        if (t + 1 < nt) STAGE_HALF(cur ^ 1, (t + 1) << 5, 1);

#pragma unroll
        for (int i = 2; i < 4; ++i)
#pragma unroll
            for (int j = 0; j < 4; ++j) {
                accP[i][j] = __builtin_amdgcn_mfma_f32_16x16x32_f16(ah[i], bh[j], accP[i][j], 0, 0, 0);
                accQ[i][j] = __builtin_amdgcn_mfma_f32_16x16x32_f16(ah[i], bl[j], accQ[i][j], 0, 0, 0);
                accQ[i][j] = __builtin_amdgcn_mfma_f32_16x16x32_f16(al[i], bh[j], accQ[i][j], 0, 0, 0);
            }
        cur ^= 1;
    }

    // epilogue: C/D layout col = lane&15, row = quad*4 + reg
#pragma unroll
    for (int i = 0; i < 4; ++i) {
        const int row = row0 + wm * 64 + i * 16 + quad * 4;
#pragma unroll
        for (int j = 0; j < 4; ++j) {
            const int col = col0 + wn * 64 + j * 16 + l16;
            const float bv = bias[col];
#pragma unroll
            for (int r = 0; r < 4; ++r)
                C[(size_t)(row + r) * N + col] = accP[i][j][r] + accQ[i][j][r] * LO_INV + bv;
        }
    }
}

// ---------------- single-precision f16 MFMA GEMM (decoder): C = A @ W + bias ----------------
// v2 structure + T1 XCD swizzle.
__global__ __launch_bounds__(256, 2) void mfma_gemm_dec(
    const ushort_t* __restrict__ A, const ushort_t* __restrict__ Wt,
    const float* __restrict__ bias, float* __restrict__ C,
    int M, int N, int K)
{
    const int NB = N >> 7;
    const int lb = xcd_swizzle(blockIdx.x, gridDim.x);
    const int mb = lb / NB;
    const int nb = lb % NB;

    __shared__ __align__(16) ushort_t As[2][128 * 32];
    __shared__ __align__(16) ushort_t Bs[2][128 * 32];

    const int tid  = threadIdx.x;
    const int lane = tid & 63;
    const int wave = tid >> 6;
    const int quad = lane >> 4;
    const int l16  = lane & 15;
    const int wm   = wave >> 1;
    const int wn   = wave & 1;

    const int row0 = mb * 128;
    const int col0 = nb * 128;

    f32x4 acc[4][4] = {};

    auto STAGE = [&](int buf, int k0) {
#pragma unroll
        for (int i = 0; i < 2; ++i) {
            const int c  = tid + i * 256;
            const int r  = c >> 2;
            const int kc = (c & 3) ^ ((r >> 1) & 3);
            gload_lds16(A  + (size_t)(row0 + r) * K + k0 + kc * 8, &As[buf][c * 8]);
            gload_lds16(Wt + (size_t)(col0 + r) * K + k0 + kc * 8, &Bs[buf][c * 8]);
        }
    };

    const int nt = K >> 5;
    STAGE(0, 0);
    int cur = 0;
    const int gq = (quad ^ ((l16 >> 1) & 3)) * 8;

    for (int t = 0; t < nt; ++t) {
        __syncthreads();

        f16x8 af[4], bf[4];
#pragma unroll
        for (int i = 0; i < 4; ++i)
            af[i] = *(const f16x8*)&As[cur][(wm * 64 + i * 16 + l16) * 32 + gq];
#pragma unroll
        for (int j = 0; j < 4; ++j)
            bf[j] = *(const f16x8*)&Bs[cur][(wn * 64 + j * 16 + l16) * 32 + gq];

        if (t + 1 < nt) STAGE(cur ^ 1, (t + 1) << 5);

#pragma unroll
        for (int i = 0; i < 4; ++i)
#pragma unroll
            for (int j = 0; j < 4; ++j)
                acc[i][j] = __builtin_amdgcn_mfma_f32_16x16x32_f16(af[i], bf[j], acc[i][j], 0, 0, 0);
        cur ^= 1;
    }

#pragma unroll
    for (int i = 0; i < 4; ++i) {
        const int row = row0 + wm * 64 + i * 16 + quad * 4;
#pragma unroll
        for (int j = 0; j < 4; ++j) {
            const int col = col0 + wn * 64 + j * 16 + l16;
            const float bv = bias[col];
#pragma unroll
            for (int r = 0; r < 4; ++r)
                C[(size_t)(row + r) * N + col] = acc[i][j][r] + bv;
        }
    }
}

// ---------------- BRC scan: 1 elem/thread, 8-deep prefetch, fast transcendentals ----------------
// fp32 gates in, y out as f16 hi (+ optional lo plane), fp32 recurrence.
template <bool WRITE_LO>
__global__ __launch_bounds__(256) void brc_scan_v3(
    const float* __restrict__ xa, const float* __restrict__ xc,
    const float* __restrict__ xh, const float* __restrict__ wa,
    const float* __restrict__ wc, const float* __restrict__ h_in,
    ushort_t* __restrict__ yhi, ushort_t* __restrict__ ylo,
    float* __restrict__ h_out, int T_c)
{
    const int idx = blockIdx.x * 256 + threadIdx.x;   // 0..BH-1
    const int j = idx & (H_DIM - 1);
    float h = h_in[idx];
    const float waj = wa[j], wcj = wc[j];

    float pa[8], pc[8], ph[8];
#pragma unroll
    for (int d = 0; d < 8; ++d) {
        const int dd = (d < T_c) ? d : 0;
        const size_t b = (size_t)dd * BH + idx;
        pa[d] = xa[b]; pc[d] = xc[b]; ph[d] = xh[b];
    }

#pragma unroll 8
    for (int t = 0; t < T_c; ++t) {
        const int s = t & 7;
        const float ca = pa[s], cc = pc[s], ch = ph[s];
        const int tn = t + 8;
        if (tn < T_c) {
            const size_t b = (size_t)tn * BH + idx;
            pa[s] = xa[b]; pc[s] = xc[b]; ph[s] = xh[b];
        }
        const float a = 1.f + ftanh(ca + waj * h);
        const float c = fsig(cc + wcj * h);
        h = c * h + (1.f - c) * ftanh(ch + a * h);

        ushort_t hh, hl;
        split_f16(h, hh, hl);
        const size_t ob = (size_t)t * BH + idx;
        yhi[ob] = hh;
        if (WRITE_LO) ylo[ob] = hl;
    }
    h_out[idx] = h;
}

extern "C" void kernel_launch(void* const* d_in, const int* in_sizes, int n_in,
                              void* d_out, int out_size, void* d_ws, size_t ws_size,
                              hipStream_t stream) {
    const float* x    = (const float*)d_in[0];   // [S,B,IN]
    const float* h0   = (const float*)d_in[1];   // [L,B,H]
    const float* Ua0  = (const float*)d_in[2];
    const float* Uc0  = (const float*)d_in[3];
    const float* Uh0  = (const float*)d_in[4];
    const float* wa0  = (const float*)d_in[5];
    const float* wc0  = (const float*)d_in[6];
    const float* ba0  = (const float*)d_in[7];
    const float* bc0  = (const float*)d_in[8];
    const float* bh0  = (const float*)d_in[9];
    const float* Ua1  = (const float*)d_in[10];
    const float* Uc1  = (const float*)d_in[11];
    const float* Uh1  = (const float*)d_in[12];
    const float* wa1  = (const float*)d_in[13];
    const float* wc1  = (const float*)d_in[14];
    const float* ba1  = (const float*)d_in[15];
    const float* bc1  = (const float*)d_in[16];
    const float* bh1  = (const float*)d_in[17];
    const float* Wdec = (const float*)d_in[18];
    const float* bdec = (const float*)d_in[19];

    float* outF = (float*)d_out;
    float* out_seq  = outF;                                   // [S,B,OUT]
    float* h_last0  = outF + (size_t)S_DIM * B_DIM * OUT_DIM; // [B,H]
    float* h_last1  = h_last0 + BH;                           // [B,H]

    // ---- workspace carve-up ----
    char* wsb = (char*)d_ws;
    size_t off = 0;
    auto alloc = [&](size_t bytes) -> void* {
        void* p = wsb + off;
        off += (bytes + 255) & ~(size_t)255;
        return p;
    };
    const size_t szL0 = (size_t)IN_DIM * H_DIM;
    const size_t szL1 = (size_t)H_DIM * H_DIM;
    const size_t szD  = (size_t)H_DIM * OUT_DIM;
    ushort_t *Wa0h = (ushort_t*)alloc(szL0 * 2), *Wa0l = (ushort_t*)alloc(szL0 * 2);
    ushort_t *Wc0h = (ushort_t*)alloc(szL0 * 2), *Wc0l = (ushort_t*)alloc(szL0 * 2);
    ushort_t *Wh0h = (ushort_t*)alloc(szL0 * 2), *Wh0l = (ushort_t*)alloc(szL0 * 2);
    ushort_t *Wa1h = (ushort_t*)alloc(szL1 * 2), *Wa1l = (ushort_t*)alloc(szL1 * 2);
    ushort_t *Wc1h = (ushort_t*)alloc(szL1 * 2), *Wc1l = (ushort_t*)alloc(szL1 * 2);
    ushort_t *Wh1h = (ushort_t*)alloc(szL1 * 2), *Wh1l = (ushort_t*)alloc(szL1 * 2);
    ushort_t *Wdh  = (ushort_t*)alloc(szD * 2),  *Wdl  = (ushort_t*)alloc(szD * 2);

    // Per-chunk bytes: x hi/lo + 3 fp32 gate planes + y0 hi/lo + y1 hi (no y1 lo)
    const size_t perT = (size_t)2 * B_DIM * IN_DIM * 2 + (size_t)3 * BH * 4 + (size_t)3 * BH * 2;
    int T_c = 512;
    while (T_c > 1 && off + (size_t)T_c * perT + 4096 > ws_size) T_c >>= 1;
    const size_t chunk_elems = (size_t)T_c * BH;
    const size_t xchunk_elems = (size_t)T_c * B_DIM * IN_DIM;

    ushort_t* xhib = (ushort_t*)alloc(xchunk_elems * 2);
    ushort_t* xlob = (ushort_t*)alloc(xchunk_elems * 2);
    float* g_a = (float*)alloc(chunk_elems * 4);
    float* g_c = (float*)alloc(chunk_elems * 4);
    float* g_h = (float*)alloc(chunk_elems * 4);
    ushort_t* y0h = (ushort_t*)alloc(chunk_elems * 2);
    ushort_t* y0l = (ushort_t*)alloc(chunk_elems * 2);
    ushort_t* y1h = (ushort_t*)alloc(chunk_elems * 2);

    const int n_chunks = S_DIM / T_c;
    const int Mc = T_c * B_DIM;

    // ---- one-time per call: weight transpose+split ----
    transpose_split_f16<<<dim3(H_DIM / 32, IN_DIM / 32), 256, 0, stream>>>(Ua0, Wa0h, Wa0l, IN_DIM, H_DIM);
    transpose_split_f16<<<dim3(H_DIM / 32, IN_DIM / 32), 256, 0, stream>>>(Uc0, Wc0h, Wc0l, IN_DIM, H_DIM);
    transpose_split_f16<<<dim3(H_DIM / 32, IN_DIM / 32), 256, 0, stream>>>(Uh0, Wh0h, Wh0l, IN_DIM, H_DIM);
    transpose_split_f16<<<dim3(H_DIM / 32, H_DIM / 32), 256, 0, stream>>>(Ua1, Wa1h, Wa1l, H_DIM, H_DIM);
    transpose_split_f16<<<dim3(H_DIM / 32, H_DIM / 32), 256, 0, stream>>>(Uc1, Wc1h, Wc1l, H_DIM, H_DIM);
    transpose_split_f16<<<dim3(H_DIM / 32, H_DIM / 32), 256, 0, stream>>>(Uh1, Wh1h, Wh1l, H_DIM, H_DIM);
    transpose_split_f16<<<dim3(OUT_DIM / 32, H_DIM / 32), 256, 0, stream>>>(Wdec, Wdh, Wdl, H_DIM, OUT_DIM);

    dim3 blk(256);
    const int grid_g = (H_DIM / 128) * (Mc / 128) * 3;   // 1D swizzled (multiple of 8)
    const int grid_d = (OUT_DIM / 128) * (Mc / 128);
    dim3 grid_scan(BH / 256);

    for (int ci = 0; ci < n_chunks; ++ci) {
        const float* x_chunk = x + (size_t)ci * Mc * IN_DIM;
        float* out_chunk = out_seq + (size_t)ci * Mc * OUT_DIM;

        // split x chunk -> hi/lo f16 planes
        convert_split_f16<<<dim3((int)(xchunk_elems / 4 / 256)), blk, 0, stream>>>(
            x_chunk, xhib, xlob, (int)xchunk_elems);

        // layer 0 gates: x @ U{a,c,h}0 + b -> fp32 gate buffers
        mfma_gemm3_split<<<dim3(grid_g), blk, 0, stream>>>(
            xhib, xlob, Wa0h, Wa0l, Wc0h, Wc0l, Wh0h, Wh0l,
            ba0, bc0, bh0, g_a, g_c, g_h, Mc, H_DIM, IN_DIM);
        brc_scan_v3<true><<<grid_scan, blk, 0, stream>>>(
            g_a, g_c, g_h, wa0, wc0, (ci == 0) ? h0 : h_last0, y0h, y0l, h_last0, T_c);

        // layer 1 gates: y0 @ U{a,c,h}1 + b
        mfma_gemm3_split<<<dim3(grid_g), blk, 0, stream>>>(
            y0h, y0l, Wa1h, Wa1l, Wc1h, Wc1l, Wh1h, Wh1l,
            ba1, bc1, bh1, g_a, g_c, g_h, Mc, H_DIM, H_DIM);
        brc_scan_v3<false><<<grid_scan, blk, 0, stream>>>(
            g_a, g_c, g_h, wa1, wc1, (ci == 0) ? (h0 + BH) : h_last1, y1h, nullptr, h_last1, T_c);

        // decoder: y1(hi) @ Wdec + bdec -> fp32 out
        mfma_gemm_dec<<<dim3(grid_d), blk, 0, stream>>>(
            y1h, Wdh, bdec, out_chunk, Mc, OUT_DIM, H_DIM);
    }
}